// Round 1
// 369.711 us; speedup vs baseline: 1.0033x; 1.0033x over previous
//
#include <hip/hip_runtime.h>
#include <hip/hip_bf16.h>

#define NHEADS 8
#define DK 64
#define DV 64
#define CIN 512
#define PIX_PER_IMG 4096
#define NPIX 65536

typedef short bf16x8 __attribute__((ext_vector_type(8)));
typedef float f32x4 __attribute__((ext_vector_type(4)));

__device__ __forceinline__ float b2f(unsigned int u) {
  union { unsigned int i; float f; } v; v.i = u << 16; return v.f;
}
__device__ __forceinline__ unsigned short f2b(float f) {
  union { float f; unsigned int i; } v; v.f = f;
  unsigned int x = v.i;
  return (unsigned short)((x + 0x7fffu + ((x >> 16) & 1u)) >> 16);
}
__device__ __forceinline__ void gload_lds16(const void* g, void* l) {
  __builtin_amdgcn_global_load_lds(
      (const __attribute__((address_space(1))) void*)g,
      (__attribute__((address_space(3))) void*)l, 16, 0, 0);
}

// ---------------- K1: pooled sums (partial) + x -> bf16, + weight prep ------
// partial layout: [4096 chunks][512 c]  (2 half-chunks per 32-pixel block)
// blocks >= 2048 do the weight transposes (old K3).
__global__ __launch_bounds__(256) void k_pool_prep(
    const float* __restrict__ x, unsigned short* __restrict__ xb,
    float* __restrict__ partial,
    const float* __restrict__ Wv, const float* __restrict__ Wo,
    unsigned short* __restrict__ WvT, unsigned short* __restrict__ WoT) {
  int blk = blockIdx.x;
  int t = threadIdx.x;
  if (blk >= 2048) {                         // 1152 prep blocks
    int idx = (blk - 2048) * 256 + t;        // 0 .. 294911
    if (idx < 262144) {
      int n = idx >> 9, c = idx & 511;       // WvT[n][c] = Wv[c][n]
      WvT[idx] = f2b(Wv[(size_t)c * 512 + n]);
    } else {
      int j = idx - 262144;                  // 32768: WoT[o][k] = Wo[k][o]
      int o = j >> 6, kk = j & 63;
      WoT[j] = f2b(Wo[(size_t)kk * 512 + o]);
    }
    return;
  }
  int b = blk >> 7, chunk = blk & 127;       // 128 chunks of 32 pixels
  int c4 = t & 127;                          // float4 index within row
  int half = t >> 7;                         // pixel parity
  size_t rowbase = (size_t)b * PIX_PER_IMG + chunk * 32;
  const float4* x4 = (const float4*)x;
  float4 acc = make_float4(0.f, 0.f, 0.f, 0.f);
#pragma unroll
  for (int i = 0; i < 16; ++i) {
    int p = 2 * i + half;
    float4 v = x4[(rowbase + p) * 128 + c4];
    acc.x += v.x; acc.y += v.y; acc.z += v.z; acc.w += v.w;
    uint2 o;
    o.x = (unsigned)f2b(v.x) | ((unsigned)f2b(v.y) << 16);
    o.y = (unsigned)f2b(v.z) | ((unsigned)f2b(v.w) << 16);
    *(uint2*)(xb + (rowbase + p) * CIN + c4 * 4) = o;
  }
  *(float4*)(partial + ((size_t)(blk * 2 + half)) * CIN + c4 * 4) = acc;
}

// ---------------- K2: xbar -> q -> P  (one block per (b,n)) -----------------
// s0 (= q . bk) removed: constant per (b,n) -> softmax-shift-invariant.
__global__ __launch_bounds__(256) void k_qp2(
    const float* __restrict__ partial,
    const float* __restrict__ Wq, const float* __restrict__ bq,
    const float* __restrict__ Wk, float* __restrict__ P) {
  __shared__ float xs[CIN];
  __shared__ float red[256];
  __shared__ float qsh[64];
  int b = blockIdx.x, n = blockIdx.y, t = threadIdx.x;
  for (int c = t; c < CIN; c += 256) {
    float s = 0.f;
    for (int ch = 0; ch < 256; ++ch) s += partial[((size_t)(b * 256 + ch)) * CIN + c];
    xs[c] = s * (1.0f / 4096.0f);
  }
  __syncthreads();
  int jj = t & 63, part = t >> 6;
  {
    float acc = 0.f;
    const float* wp = Wq + (size_t)(part * 128) * CIN + n * 64 + jj;
    for (int ci = 0; ci < 128; ++ci)
      acc += xs[part * 128 + ci] * wp[(size_t)ci * CIN];
    red[t] = acc;
  }
  __syncthreads();
  if (t < 64)
    qsh[t] = red[t] + red[t + 64] + red[t + 128] + red[t + 192] + bq[n * 64 + t];
  __syncthreads();
  for (int c = t; c < CIN; c += 256) {
    float acc = 0.f;
    const float* wr = Wk + (size_t)c * CIN + n * 64;
    for (int k = 0; k < 64; ++k) acc += qsh[k] * wr[k];
    P[((size_t)(b * NHEADS + n)) * CIN + c] = acc;
  }
}

// ---------------- K4: scores via MFMA ---------------------------------------
// s[b,n,pix] = 0.125 * (xb[pix,:] . P[b,n,:])  as GEMM M=64/block, N=8(pad16), K=512.
// A-frags straight from global (16 rows x 64B per instr). B = P staged in LDS
// as hi/lo bf16 split (rows 0..7 hi, 8..15 lo) for fp32-grade P precision.
__global__ __launch_bounds__(256) void k_scores(
    const unsigned short* __restrict__ xb, const float* __restrict__ P,
    float* __restrict__ s) {
  __shared__ __align__(16) unsigned short Pl[24 * 520];   // rows 16..23 unused pad
  int blk = blockIdx.x;                 // 1024 = 16 b * 64 tiles of 64 pixels
  int b = blk >> 6, tile = blk & 63;
  int t = threadIdx.x;
  for (int i = t; i < 4096; i += 256) { // stage P[b]: 8 x 512
    int n = i >> 9, c = i & 511;
    float pv = P[((size_t)(b * NHEADS + n)) * CIN + c];
    unsigned short h = f2b(pv);
    Pl[n * 520 + c] = h;
    Pl[(n + 8) * 520 + c] = f2b(pv - b2f(h));
  }
  __syncthreads();
  int wave = t >> 6, lane = t & 63;
  int prow = lane & 15, kgrp = lane >> 4;
  const unsigned short* arow =
      xb + ((size_t)b * PIX_PER_IMG + tile * 64 + wave * 16 + prow) * CIN + kgrp * 8;
  const unsigned short* bhi = Pl + prow * 520 + kgrp * 8;
  const unsigned short* blo = Pl + (prow + 8) * 520 + kgrp * 8;
  f32x4 acc = (f32x4){0.f, 0.f, 0.f, 0.f};
#pragma unroll
  for (int kb = 0; kb < 16; ++kb) {
    bf16x8 af = *(const bf16x8*)(arow + kb * 32);
    bf16x8 bh = *(const bf16x8*)(bhi + kb * 32);
    bf16x8 bl = *(const bf16x8*)(blo + kb * 32);
    acc = __builtin_amdgcn_mfma_f32_16x16x32_bf16(af, bh, acc, 0, 0, 0);
    acc = __builtin_amdgcn_mfma_f32_16x16x32_bf16(af, bl, acc, 0, 0, 0);
  }
  // D: col = lane&15 = n (valid n<8), row = kgrp*4 + r = pixel within wave tile
  int n = prow;
  if (n < 8) {
    float* sp = s + ((size_t)(b * NHEADS + n)) * PIX_PER_IMG + tile * 64 + wave * 16 + kgrp * 4;
#pragma unroll
    for (int r = 0; r < 4; ++r) sp[r] = acc[r] * 0.125f;
  }
}

// ---------------- K5: row softmax -> ah ; col softmax -> avT ----------------
// 256 threads: 128 tasks (64 rows + 64 cols), 2 lanes/task, shfl_xor reduce.
__global__ __launch_bounds__(256) void k_softmax(
    const float* __restrict__ s, float* __restrict__ ah, float* __restrict__ avT) {
  __shared__ float st[4096];
  int bn = blockIdx.x, t = threadIdx.x;
  const float* sp = s + (size_t)bn * 4096;
  for (int i = t; i < 4096; i += 256) st[i] = sp[i];
  __syncthreads();
  int task = t >> 1, half = t & 1;
  int id = task & 63;
  bool isRow = task < 64;
  float v[32];
#pragma unroll
  for (int i = 0; i < 32; ++i) {
    int e = half * 32 + i;
    v[i] = isRow ? st[id * 64 + e] : st[e * 64 + id];
  }
  float m = -1e30f;
#pragma unroll
  for (int i = 0; i < 32; ++i) m = fmaxf(m, v[i]);
  m = fmaxf(m, __shfl_xor(m, 1));
  float sum = 0.f;
#pragma unroll
  for (int i = 0; i < 32; ++i) { v[i] = __expf(v[i] - m); sum += v[i]; }
  sum += __shfl_xor(sum, 1);
  float inv = 1.f / sum;
  float* dst = (isRow ? ah : avT) + (size_t)bn * 4096 + id * 64 + half * 32;
#pragma unroll
  for (int i = 0; i < 32; ++i) dst[i] = v[i] * inv;
}

// ---------------- K6: fused xh/xv weighted sums -----------------------------
// blockIdx.x < 1024: xh[n][b*64+h][c] = sum_w ah[n,h,w]*x[b,h,w,c]
// blockIdx.x >= 1024: xv[n][b*64+w][c] = sum_h avT[n,w,h]*x[b,h,w,c]
// XHV layout: [n][2048][512] bf16; rows 0..1023 = (b,h), 1024..2047 = (b,w)
__global__ __launch_bounds__(256) void k_xhv(
    const unsigned short* __restrict__ xb, const float* __restrict__ ahg,
    const float* __restrict__ avTg, unsigned short* __restrict__ XHV) {
  __shared__ unsigned short xs[64 * 256];   // [pix][256 c] 32 KB
  __shared__ float al[NHEADS * 64];
  int bx = blockIdx.x, ch = blockIdx.y, t = threadIdx.x;
  bool isV = bx >= 1024;
  int bi = isV ? bx - 1024 : bx;
  int b = bi >> 6, rc = bi & 63;            // rc = h (row pass) or w (col pass)
  if (!isV) {
    const unsigned short* src = xb + ((size_t)(b * PIX_PER_IMG + rc * 64)) * CIN + ch * 256;
#pragma unroll
    for (int i = 0; i < 8; ++i) {
      int idx = i * 256 + t;
      int w = idx >> 5, off = idx & 31;
      ((uint4*)xs)[idx] = ((const uint4*)(src + (size_t)w * CIN))[off];
    }
  } else {
#pragma unroll
    for (int i = 0; i < 8; ++i) {
      int idx = i * 256 + t;
      int h = idx >> 5, off = idx & 31;
      ((uint4*)xs)[idx] =
          ((const uint4*)(xb + ((size_t)(b * PIX_PER_IMG + h * 64 + rc)) * CIN + ch * 256))[off];
    }
  }
  const float* ag = isV ? avTg : ahg;
#pragma unroll
  for (int i = 0; i < 2; ++i) {
    int idx = i * 256 + t;
    al[idx] = ag[((size_t)(b * NHEADS + (idx >> 6))) * PIX_PER_IMG + rc * 64 + (idx & 63)];
  }
  __syncthreads();
  int n = t >> 5, oct = t & 31;
  float acc[8] = {0.f, 0.f, 0.f, 0.f, 0.f, 0.f, 0.f, 0.f};
  const float* ar = al + n * 64;
  for (int p = 0; p < 64; ++p) {
    float aw = ar[p];
    uint4 u = *(const uint4*)(xs + (size_t)p * 256 + oct * 8);
    acc[0] += aw * b2f(u.x & 0xffff);
    acc[1] += aw * b2f(u.x >> 16);
    acc[2] += aw * b2f(u.y & 0xffff);
    acc[3] += aw * b2f(u.y >> 16);
    acc[4] += aw * b2f(u.z & 0xffff);
    acc[5] += aw * b2f(u.z >> 16);
    acc[6] += aw * b2f(u.w & 0xffff);
    acc[7] += aw * b2f(u.w >> 16);
  }
  uint4 o;
  o.x = (unsigned)f2b(acc[0]) | ((unsigned)f2b(acc[1]) << 16);
  o.y = (unsigned)f2b(acc[2]) | ((unsigned)f2b(acc[3]) << 16);
  o.z = (unsigned)f2b(acc[4]) | ((unsigned)f2b(acc[5]) << 16);
  o.w = (unsigned)f2b(acc[6]) | ((unsigned)f2b(acc[7]) << 16);
  size_t dst = ((size_t)(n * 2048 + (isV ? 1024 : 0) + b * 64 + rc)) * CIN + ch * 256 + oct * 8;
  *(uint4*)(XHV + dst) = o;
}

// ---------------- K7: batched skinny GEMM: per head, [2048x512]@[512x64] ----
__global__ __launch_bounds__(256) void k_gemm2(
    const unsigned short* __restrict__ XHV, const unsigned short* __restrict__ WvT,
    const float* __restrict__ bv, float* __restrict__ Ah, float* __restrict__ Av) {
  __shared__ __align__(16) unsigned short As[128 * 64];   // 16 KB
  __shared__ __align__(16) unsigned short Bs[64 * 64];    // 8 KB
  const int t = threadIdx.x;
  const int wave = t >> 6, lane = t & 63;
  const int mtile = blockIdx.x, head = blockIdx.y;
  const int m0 = mtile * 128;
  const unsigned short* A = XHV + (size_t)head * 2048 * CIN;
  const unsigned short* BT = WvT + (size_t)head * 64 * CIN;

  f32x4 acc[2][4];
  for (int i = 0; i < 2; ++i)
    for (int j = 0; j < 4; ++j) acc[i][j] = (f32x4){0.f, 0.f, 0.f, 0.f};

  const int lrow = wave * 8 + (lane >> 3);
  const int lcolb = (lane & 7) * 16;

  for (int kt = 0; kt < 8; ++kt) {
    __syncthreads();
#pragma unroll
    for (int j = 0; j < 4; ++j) {
      gload_lds16((const char*)A + ((size_t)(m0 + j * 32 + lrow) * CIN + kt * 64) * 2 + lcolb,
                  (char*)As + (j * 32 + wave * 8) * 128);
    }
#pragma unroll
    for (int j = 0; j < 2; ++j) {
      gload_lds16((const char*)BT + ((size_t)(j * 32 + lrow) * CIN + kt * 64) * 2 + lcolb,
                  (char*)Bs + (j * 32 + wave * 8) * 128);
    }
    __syncthreads();
#pragma unroll
    for (int s = 0; s < 2; ++s) {
      bf16x8 af[2], bg[4];
#pragma unroll
      for (int i = 0; i < 2; ++i) {
        int mrow = wave * 32 + i * 16 + (lane & 15);
        af[i] = *(const bf16x8*)((const char*)As + mrow * 128 + s * 64 + ((lane >> 4) * 16));
      }
#pragma unroll
      for (int j = 0; j < 4; ++j) {
        int nrow = j * 16 + (lane & 15);
        bg[j] = *(const bf16x8*)((const char*)Bs + nrow * 128 + s * 64 + ((lane >> 4) * 16));
      }
#pragma unroll
      for (int i = 0; i < 2; ++i)
#pragma unroll
        for (int j = 0; j < 4; ++j)
          acc[i][j] = __builtin_amdgcn_mfma_f32_16x16x32_bf16(af[i], bg[j], acc[i][j], 0, 0, 0);
    }
  }
#pragma unroll
  for (int i = 0; i < 2; ++i)
#pragma unroll
    for (int j = 0; j < 4; ++j) {
      int v = j * 16 + (lane & 15);
      float bb = bv[head * 64 + v];
#pragma unroll
      for (int r = 0; r < 4; ++r) {
        int m = m0 + wave * 32 + i * 16 + ((lane >> 4) * 4) + r;   // 0..2047
        float val = acc[i][j][r] + bb;
        if (m < 1024) {
          int b = m >> 6, h = m & 63;
          Ah[((size_t)(b * NHEADS + head)) * 4096 + h * 64 + v] = val;
        } else {
          int m2 = m - 1024;
          int b = m2 >> 6, w = m2 & 63;
          Av[((size_t)(b * NHEADS + head)) * 4096 + w * 64 + v] = val;
        }
      }
    }
}

// ---------------- K8: fused combine + out-GEMM ------------------------------
__global__ __launch_bounds__(256) void k_outgemm(
    const float* __restrict__ Ah, const float* __restrict__ Av,
    const unsigned short* __restrict__ WoT,
    const float* __restrict__ bo, float* __restrict__ out) {
  __shared__ __align__(16) unsigned short As[128 * 64];
  __shared__ __align__(16) unsigned short Bs[128 * 64];
  const int t = threadIdx.x;
  const int wave = t >> 6, lane = t & 63;
  const int wr = wave >> 1, wc = wave & 1;
  const int m0 = blockIdx.y * 128, n0 = blockIdx.x * 128;
  const int b = m0 >> 12, h0 = (m0 >> 6) & 63;

  const int srow = wave * 32 + (lane >> 3), scolb = (lane & 7) * 16;
#pragma unroll
  for (int j = 0; j < 4; ++j)
    gload_lds16((const char*)WoT + ((size_t)(n0 + srow + j * 8) * 64) * 2 + scolb,
                (char*)Bs + wave * 4096 + j * 1024);

  {
    const int v = t & 63, rg = t >> 6;
    float ahv0[8], ahv1[8];
#pragma unroll
    for (int n = 0; n < 8; ++n) {
      ahv0[n] = Ah[((size_t)((b * 8 + n) * 64 + h0)) * 64 + v];
      ahv1[n] = Ah[((size_t)((b * 8 + n) * 64 + h0 + 1)) * 64 + v];
    }
#pragma unroll 2
    for (int i = 0; i < 16; ++i) {
      int w = rg * 16 + i;
      float a0 = 0.f, a1 = 0.f;
#pragma unroll
      for (int n = 0; n < 8; ++n) {
        float av = Av[((size_t)((b * 8 + n) * 64 + w)) * 64 + v];
        a0 += ahv0[n] * av;
        a1 += ahv1[n] * av;
      }
      As[w * 64 + v] = f2b(a0);
      As[(64 + w) * 64 + v] = f2b(a1);
    }
  }
  __syncthreads();

  f32x4 acc[4][4];
  for (int i = 0; i < 4; ++i)
    for (int j = 0; j < 4; ++j) acc[i][j] = (f32x4){0.f, 0.f, 0.f, 0.f};
#pragma unroll
  for (int s = 0; s < 2; ++s) {
    bf16x8 af[4], bg[4];
#pragma unroll
    for (int i = 0; i < 4; ++i) {
      int mrow = wr * 64 + i * 16 + (lane & 15);
      af[i] = *(const bf16x8*)((const char*)As + mrow * 128 + s * 64 + ((lane >> 4) * 16));
    }
#pragma unroll
    for (int j = 0; j < 4; ++j) {
      int nrow = wc * 64 + j * 16 + (lane & 15);
      bg[j] = *(const bf16x8*)((const char*)Bs + nrow * 128 + s * 64 + ((lane >> 4) * 16));
    }
#pragma unroll
    for (int i = 0; i < 4; ++i)
#pragma unroll
      for (int j = 0; j < 4; ++j)
        acc[i][j] = __builtin_amdgcn_mfma_f32_16x16x32_bf16(af[i], bg[j], acc[i][j], 0, 0, 0);
  }
#pragma unroll
  for (int i = 0; i < 4; ++i)
#pragma unroll
    for (int j = 0; j < 4; ++j) {
      int mbase = m0 + wr * 64 + i * 16 + ((lane >> 4) * 4);
      int n = n0 + wc * 64 + j * 16 + (lane & 15);
      float bb = bo[n];
#pragma unroll
      for (int r = 0; r < 4; ++r)
        out[(size_t)(mbase + r) * 512 + n] = acc[i][j][r] + bb;
    }
}

extern "C" void kernel_launch(void* const* d_in, const int* in_sizes, int n_in,
                              void* d_out, int out_size, void* d_ws, size_t ws_size,
                              hipStream_t stream) {
  (void)in_sizes; (void)n_in; (void)out_size; (void)ws_size;
  const float* x = (const float*)d_in[0];
  const float* Wq = (const float*)d_in[1];
  const float* bq = (const float*)d_in[2];
  const float* Wk = (const float*)d_in[3];
  // const float* bk = (const float*)d_in[4];   // s0 is softmax-shift-invariant: unused
  const float* Wv = (const float*)d_in[5];
  const float* bv = (const float*)d_in[6];
  const float* Wo = (const float*)d_in[7];
  const float* bo = (const float*)d_in[8];
  float* out = (float*)d_out;

  char* ws = (char*)d_ws;
  unsigned short* xb = (unsigned short*)(ws + 0);            // 67,108,864
  float* partial = (float*)(ws + 67108864);                  //  8,388,608
  float* s = (float*)(ws + 75497472);                        //  2,097,152
  float* P = (float*)(ws + 77594624);                        //    262,144
  float* attn_h = (float*)(ws + 77856768);                   //  2,097,152
  float* avT = (float*)(ws + 79953920);                      //  2,097,152
  unsigned short* XHV = (unsigned short*)(ws + 82051072);    // 16,777,216
  float* Ah = (float*)(ws + 98828288);                       //  2,097,152
  float* Av = (float*)(ws + 100925440);                      //  2,097,152
  unsigned short* WvT = (unsigned short*)(ws + 103022592);   //    524,288
  unsigned short* WoT = (unsigned short*)(ws + 103546880);   //     65,536
  // total ws use ~103.6 MB

  k_pool_prep<<<3200, 256, 0, stream>>>(x, xb, partial, Wv, Wo, WvT, WoT);
  k_qp2<<<dim3(16, 8), 256, 0, stream>>>(partial, Wq, bq, Wk, P);
  k_scores<<<1024, 256, 0, stream>>>(xb, P, s);
  k_softmax<<<128, 256, 0, stream>>>(s, attn_h, avT);
  k_xhv<<<dim3(2048, 2), 256, 0, stream>>>(xb, attn_h, avT, XHV);
  k_gemm2<<<dim3(16, 8), 256, 0, stream>>>(XHV, WvT, bv, Ah, Av);
  k_outgemm<<<dim3(4, 512), 256, 0, stream>>>(Ah, Av, WoT, bo, out);
}

// Round 2
// 348.883 us; speedup vs baseline: 1.0632x; 1.0597x over previous
//
#include <hip/hip_runtime.h>
#include <hip/hip_bf16.h>

#define NHEADS 8
#define DK 64
#define DV 64
#define CIN 512
#define PIX_PER_IMG 4096
#define NPIX 65536

typedef short bf16x8 __attribute__((ext_vector_type(8)));
typedef float f32x4 __attribute__((ext_vector_type(4)));

__device__ __forceinline__ float b2f(unsigned int u) {
  union { unsigned int i; float f; } v; v.i = u << 16; return v.f;
}
__device__ __forceinline__ unsigned short f2b(float f) {
  union { float f; unsigned int i; } v; v.f = f;
  unsigned int x = v.i;
  return (unsigned short)((x + 0x7fffu + ((x >> 16) & 1u)) >> 16);
}
__device__ __forceinline__ void gload_lds16(const void* g, void* l) {
  __builtin_amdgcn_global_load_lds(
      (const __attribute__((address_space(1))) void*)g,
      (__attribute__((address_space(3))) void*)l, 16, 0, 0);
}

// ---------------- K1: pooled sums (partial) + x -> bf16, + weight prep ------
// partial layout: [2048 chunks][512 c] (one row per 32-pixel block, halves
// merged in LDS). blocks >= 2048 do the weight transposes.
__global__ __launch_bounds__(256) void k_pool_prep(
    const float* __restrict__ x, unsigned short* __restrict__ xb,
    float* __restrict__ partial,
    const float* __restrict__ Wv, const float* __restrict__ Wo,
    unsigned short* __restrict__ WvT, unsigned short* __restrict__ WoT) {
  int blk = blockIdx.x;
  int t = threadIdx.x;
  if (blk >= 2048) {                         // 1152 prep blocks
    int idx = (blk - 2048) * 256 + t;        // 0 .. 294911
    if (idx < 262144) {
      int n = idx >> 9, c = idx & 511;       // WvT[n][c] = Wv[c][n]
      WvT[idx] = f2b(Wv[(size_t)c * 512 + n]);
    } else {
      int j = idx - 262144;                  // 32768: WoT[o][k] = Wo[k][o]
      int o = j >> 6, kk = j & 63;
      WoT[j] = f2b(Wo[(size_t)kk * 512 + o]);
    }
    return;
  }
  __shared__ float4 sh[128];
  int b = blk >> 7, chunk = blk & 127;       // 128 chunks of 32 pixels
  int c4 = t & 127;                          // float4 index within row
  int half = t >> 7;                         // pixel parity
  size_t rowbase = (size_t)b * PIX_PER_IMG + chunk * 32;
  const float4* x4 = (const float4*)x;
  float4 acc = make_float4(0.f, 0.f, 0.f, 0.f);
#pragma unroll
  for (int i = 0; i < 16; ++i) {
    int p = 2 * i + half;
    float4 v = x4[(rowbase + p) * 128 + c4];
    acc.x += v.x; acc.y += v.y; acc.z += v.z; acc.w += v.w;
    uint2 o;
    o.x = (unsigned)f2b(v.x) | ((unsigned)f2b(v.y) << 16);
    o.y = (unsigned)f2b(v.z) | ((unsigned)f2b(v.w) << 16);
    *(uint2*)(xb + (rowbase + p) * CIN + c4 * 4) = o;
  }
  if (half) sh[c4] = acc;
  __syncthreads();
  if (!half) {
    float4 o = sh[c4];
    acc.x += o.x; acc.y += o.y; acc.z += o.z; acc.w += o.w;
    *(float4*)(partial + (size_t)blk * CIN + c4 * 4) = acc;
  }
}

// ---------------- K2: xbar -> q -> P (scaled)  (one block per (b,n)) --------
// P absorbs the 1/sqrt(dk)=0.125 score scale. s0 (= q.bk) removed:
// constant per (b,n) -> softmax-shift-invariant.
__global__ __launch_bounds__(256) void k_qp2(
    const float* __restrict__ partial,
    const float* __restrict__ Wq, const float* __restrict__ bq,
    const float* __restrict__ Wk, float* __restrict__ P) {
  __shared__ float xs[CIN];
  __shared__ float red[256];
  __shared__ float qsh[64];
  int b = blockIdx.x, n = blockIdx.y, t = threadIdx.x;
  for (int c = t; c < CIN; c += 256) {
    float s = 0.f;
    for (int ch = 0; ch < 128; ++ch) s += partial[((size_t)(b * 128 + ch)) * CIN + c];
    xs[c] = s * (1.0f / 4096.0f);
  }
  __syncthreads();
  int jj = t & 63, part = t >> 6;
  {
    float acc = 0.f;
    const float* wp = Wq + (size_t)(part * 128) * CIN + n * 64 + jj;
    for (int ci = 0; ci < 128; ++ci)
      acc += xs[part * 128 + ci] * wp[(size_t)ci * CIN];
    red[t] = acc;
  }
  __syncthreads();
  if (t < 64)
    qsh[t] = red[t] + red[t + 64] + red[t + 128] + red[t + 192] + bq[n * 64 + t];
  __syncthreads();
  for (int c = t; c < CIN; c += 256) {
    float acc = 0.f;
    const float* wr = Wk + (size_t)c * CIN + n * 64;
    for (int k = 0; k < 64; ++k) acc += qsh[k] * wr[k];
    P[((size_t)(b * NHEADS + n)) * CIN + c] = acc * 0.125f;
  }
}

// ---------------- K4: scores via MFMA ---------------------------------------
// s[b,n,pix] = xb[pix,:] . P[b,n,:]  as GEMM M=64/block, N=8(pad16), K=512.
// A-frags straight from global. B = P staged in LDS as hi/lo bf16 split.
__global__ __launch_bounds__(256) void k_scores(
    const unsigned short* __restrict__ xb, const float* __restrict__ P,
    float* __restrict__ s) {
  __shared__ __align__(16) unsigned short Pl[24 * 520];
  int blk = blockIdx.x;                 // 1024 = 16 b * 64 tiles of 64 pixels
  int b = blk >> 6, tile = blk & 63;
  int t = threadIdx.x;
  for (int i = t; i < 4096; i += 256) { // stage P[b]: 8 x 512
    int n = i >> 9, c = i & 511;
    float pv = P[((size_t)(b * NHEADS + n)) * CIN + c];
    unsigned short h = f2b(pv);
    Pl[n * 520 + c] = h;
    Pl[(n + 8) * 520 + c] = f2b(pv - b2f(h));
  }
  __syncthreads();
  int wave = t >> 6, lane = t & 63;
  int prow = lane & 15, kgrp = lane >> 4;
  const unsigned short* arow =
      xb + ((size_t)b * PIX_PER_IMG + tile * 64 + wave * 16 + prow) * CIN + kgrp * 8;
  const unsigned short* bhi = Pl + prow * 520 + kgrp * 8;
  const unsigned short* blo = Pl + (prow + 8) * 520 + kgrp * 8;
  f32x4 acc = (f32x4){0.f, 0.f, 0.f, 0.f};
#pragma unroll
  for (int kb = 0; kb < 16; ++kb) {
    bf16x8 af = *(const bf16x8*)(arow + kb * 32);
    bf16x8 bh = *(const bf16x8*)(bhi + kb * 32);
    bf16x8 bl = *(const bf16x8*)(blo + kb * 32);
    acc = __builtin_amdgcn_mfma_f32_16x16x32_bf16(af, bh, acc, 0, 0, 0);
    acc = __builtin_amdgcn_mfma_f32_16x16x32_bf16(af, bl, acc, 0, 0, 0);
  }
  int n = prow;
  if (n < 8) {
    float* sp = s + ((size_t)(b * NHEADS + n)) * PIX_PER_IMG + tile * 64 + wave * 16 + kgrp * 4;
#pragma unroll
    for (int r = 0; r < 4; ++r) sp[r] = acc[r];
  }
}

// ---------------- K6: fused softmax + xh/xv weighted sums -------------------
// Softmax for the block's (b, rc) slice is recomputed in-block from s
// (64-elem row/col softmax, 32-lane shfl reduce) - kills the k_softmax
// launch and the ah/avT global round-trip.
// blockIdx.x < 1024: xh[n][b*64+h][c] = sum_w softmax_w(s)*x[b,h,w,c]
// blockIdx.x >= 1024: xv[n][b*64+w][c] = sum_h softmax_h(s)*x[b,h,w,c]
// XHV layout: [n][2048][512] bf16; rows 0..1023 = (b,h), 1024..2047 = (b,w)
__global__ __launch_bounds__(256) void k_xhv(
    const unsigned short* __restrict__ xb, const float* __restrict__ s,
    unsigned short* __restrict__ XHV) {
  __shared__ unsigned short xs[64 * 256];   // [pix][256 c] 32 KB
  __shared__ float al[NHEADS * 64];
  int bx = blockIdx.x, ch = blockIdx.y, t = threadIdx.x;
  bool isV = bx >= 1024;
  int bi = isV ? bx - 1024 : bx;
  int b = bi >> 6, rc = bi & 63;            // rc = h (row pass) or w (col pass)
  if (!isV) {
    const unsigned short* src = xb + ((size_t)(b * PIX_PER_IMG + rc * 64)) * CIN + ch * 256;
#pragma unroll
    for (int i = 0; i < 8; ++i) {
      int idx = i * 256 + t;
      int w = idx >> 5, off = idx & 31;
      ((uint4*)xs)[idx] = ((const uint4*)(src + (size_t)w * CIN))[off];
    }
  } else {
#pragma unroll
    for (int i = 0; i < 8; ++i) {
      int idx = i * 256 + t;
      int h = idx >> 5, off = idx & 31;
      ((uint4*)xs)[idx] =
          ((const uint4*)(xb + ((size_t)(b * PIX_PER_IMG + h * 64 + rc)) * CIN + ch * 256))[off];
    }
  }
  {
    int n = t >> 5, l = t & 31;             // 8 heads x 32 lanes, 2 elems/lane
    const float* sp = s + ((size_t)(b * NHEADS + n)) * PIX_PER_IMG;
    float v0, v1;
    if (!isV) { v0 = sp[rc * 64 + 2 * l];  v1 = sp[rc * 64 + 2 * l + 1]; }
    else      { v0 = sp[(2 * l) * 64 + rc]; v1 = sp[(2 * l + 1) * 64 + rc]; }
    float m = fmaxf(v0, v1);
#pragma unroll
    for (int mask = 1; mask <= 16; mask <<= 1) m = fmaxf(m, __shfl_xor(m, mask));
    float e0 = __expf(v0 - m), e1 = __expf(v1 - m);
    float sm = e0 + e1;
#pragma unroll
    for (int mask = 1; mask <= 16; mask <<= 1) sm += __shfl_xor(sm, mask);
    float inv = 1.f / sm;
    al[n * 64 + 2 * l] = e0 * inv;
    al[n * 64 + 2 * l + 1] = e1 * inv;
  }
  __syncthreads();
  int n = t >> 5, oct = t & 31;
  float acc[8] = {0.f, 0.f, 0.f, 0.f, 0.f, 0.f, 0.f, 0.f};
  const float* ar = al + n * 64;
  for (int p = 0; p < 64; ++p) {
    float aw = ar[p];
    uint4 u = *(const uint4*)(xs + (size_t)p * 256 + oct * 8);
    acc[0] += aw * b2f(u.x & 0xffff);
    acc[1] += aw * b2f(u.x >> 16);
    acc[2] += aw * b2f(u.y & 0xffff);
    acc[3] += aw * b2f(u.y >> 16);
    acc[4] += aw * b2f(u.z & 0xffff);
    acc[5] += aw * b2f(u.z >> 16);
    acc[6] += aw * b2f(u.w & 0xffff);
    acc[7] += aw * b2f(u.w >> 16);
  }
  uint4 o;
  o.x = (unsigned)f2b(acc[0]) | ((unsigned)f2b(acc[1]) << 16);
  o.y = (unsigned)f2b(acc[2]) | ((unsigned)f2b(acc[3]) << 16);
  o.z = (unsigned)f2b(acc[4]) | ((unsigned)f2b(acc[5]) << 16);
  o.w = (unsigned)f2b(acc[6]) | ((unsigned)f2b(acc[7]) << 16);
  size_t dst = ((size_t)(n * 2048 + (isV ? 1024 : 0) + b * 64 + rc)) * CIN + ch * 256 + oct * 8;
  *(uint4*)(XHV + dst) = o;
}

// ---------------- K7: batched skinny GEMM: per head, [2048x512]@[512x64] ----
// 64-row m-tiles, grid (32,8)=256 blocks -> one block per CU (was 128).
__global__ __launch_bounds__(256) void k_gemm2(
    const unsigned short* __restrict__ XHV, const unsigned short* __restrict__ WvT,
    const float* __restrict__ bv, float* __restrict__ Ah, float* __restrict__ Av) {
  __shared__ __align__(16) unsigned short As[64 * 64];    // 8 KB
  __shared__ __align__(16) unsigned short Bs[64 * 64];    // 8 KB
  const int t = threadIdx.x;
  const int wave = t >> 6, lane = t & 63;
  const int m0 = blockIdx.x * 64, head = blockIdx.y;
  const unsigned short* A = XHV + (size_t)head * 2048 * CIN;
  const unsigned short* BT = WvT + (size_t)head * 64 * CIN;

  f32x4 acc[4];
  for (int j = 0; j < 4; ++j) acc[j] = (f32x4){0.f, 0.f, 0.f, 0.f};

  const int lrow = wave * 8 + (lane >> 3);
  const int lcolb = (lane & 7) * 16;

  for (int kt = 0; kt < 8; ++kt) {
    __syncthreads();
#pragma unroll
    for (int j = 0; j < 2; ++j)
      gload_lds16((const char*)A + ((size_t)(m0 + j * 32 + lrow) * CIN + kt * 64) * 2 + lcolb,
                  (char*)As + (j * 32 + wave * 8) * 128);
#pragma unroll
    for (int j = 0; j < 2; ++j)
      gload_lds16((const char*)BT + ((size_t)(j * 32 + lrow) * CIN + kt * 64) * 2 + lcolb,
                  (char*)Bs + (j * 32 + wave * 8) * 128);
    __syncthreads();
#pragma unroll
    for (int ss = 0; ss < 2; ++ss) {
      bf16x8 af = *(const bf16x8*)((const char*)As + (wave * 16 + (lane & 15)) * 128 +
                                   ss * 64 + ((lane >> 4) * 16));
      bf16x8 bg[4];
#pragma unroll
      for (int j = 0; j < 4; ++j)
        bg[j] = *(const bf16x8*)((const char*)Bs + (j * 16 + (lane & 15)) * 128 +
                                 ss * 64 + ((lane >> 4) * 16));
#pragma unroll
      for (int j = 0; j < 4; ++j)
        acc[j] = __builtin_amdgcn_mfma_f32_16x16x32_bf16(af, bg[j], acc[j], 0, 0, 0);
    }
  }
#pragma unroll
  for (int j = 0; j < 4; ++j) {
    int v = j * 16 + (lane & 15);
    float bb = bv[head * 64 + v];
#pragma unroll
    for (int r = 0; r < 4; ++r) {
      int m = m0 + wave * 16 + ((lane >> 4) * 4) + r;   // 0..2047
      float val = acc[j][r] + bb;
      if (m < 1024) {
        int b = m >> 6, h = m & 63;
        Ah[((size_t)(b * NHEADS + head)) * 4096 + h * 64 + v] = val;
      } else {
        int m2 = m - 1024;
        int b = m2 >> 6, w = m2 & 63;
        Av[((size_t)(b * NHEADS + head)) * 4096 + w * 64 + v] = val;
      }
    }
  }
}

// ---------------- K8: fused combine + out-GEMM ------------------------------
// Each block computes the As combine ONCE and loops 2 n-tiles (was 4 blocks
// each recomputing it). grid (2,512).
__global__ __launch_bounds__(256) void k_outgemm(
    const float* __restrict__ Ah, const float* __restrict__ Av,
    const unsigned short* __restrict__ WoT,
    const float* __restrict__ bo, float* __restrict__ out) {
  __shared__ __align__(16) unsigned short As[128 * 64];
  __shared__ __align__(16) unsigned short Bs[128 * 64];
  const int t = threadIdx.x;
  const int wave = t >> 6, lane = t & 63;
  const int wr = wave >> 1, wc = wave & 1;
  const int m0 = blockIdx.y * 128;
  const int b = m0 >> 12, h0 = (m0 >> 6) & 63;

  const int srow = wave * 32 + (lane >> 3), scolb = (lane & 7) * 16;
  // stage Bs for nt=0 (async, overlaps the As construct)
  {
    int n0 = blockIdx.x * 256;
#pragma unroll
    for (int j = 0; j < 4; ++j)
      gload_lds16((const char*)WoT + ((size_t)(n0 + srow + j * 8) * 64) * 2 + scolb,
                  (char*)Bs + wave * 4096 + j * 1024);
  }
  // compute As[r][v] = sum_n Ah[b,n,h(r),v] * Av[b,n,w(r),v], r = hh*64+w
  {
    const int v = t & 63, rg = t >> 6;
    float ahv0[8], ahv1[8];
#pragma unroll
    for (int n = 0; n < 8; ++n) {
      ahv0[n] = Ah[((size_t)((b * 8 + n) * 64 + h0)) * 64 + v];
      ahv1[n] = Ah[((size_t)((b * 8 + n) * 64 + h0 + 1)) * 64 + v];
    }
#pragma unroll 2
    for (int i = 0; i < 16; ++i) {
      int w = rg * 16 + i;
      float a0 = 0.f, a1 = 0.f;
#pragma unroll
      for (int n = 0; n < 8; ++n) {
        float av = Av[((size_t)((b * 8 + n) * 64 + w)) * 64 + v];
        a0 += ahv0[n] * av;
        a1 += ahv1[n] * av;
      }
      As[w * 64 + v] = f2b(a0);
      As[(64 + w) * 64 + v] = f2b(a1);
    }
  }

  for (int nt = 0; nt < 2; ++nt) {
    const int n0 = (blockIdx.x * 2 + nt) * 128;
    if (nt) {
      __syncthreads();     // prior MFMA done before Bs overwrite
#pragma unroll
      for (int j = 0; j < 4; ++j)
        gload_lds16((const char*)WoT + ((size_t)(n0 + srow + j * 8) * 64) * 2 + scolb,
                    (char*)Bs + wave * 4096 + j * 1024);
    }
    __syncthreads();       // As + Bs(nt) visible

    f32x4 acc[4][4];
    for (int i = 0; i < 4; ++i)
      for (int j = 0; j < 4; ++j) acc[i][j] = (f32x4){0.f, 0.f, 0.f, 0.f};
#pragma unroll
    for (int ss = 0; ss < 2; ++ss) {
      bf16x8 af[4], bg[4];
#pragma unroll
      for (int i = 0; i < 4; ++i) {
        int mrow = wr * 64 + i * 16 + (lane & 15);
        af[i] = *(const bf16x8*)((const char*)As + mrow * 128 + ss * 64 + ((lane >> 4) * 16));
      }
#pragma unroll
      for (int j = 0; j < 4; ++j) {
        int nrow = wc * 64 + j * 16 + (lane & 15);
        bg[j] = *(const bf16x8*)((const char*)Bs + nrow * 128 + ss * 64 + ((lane >> 4) * 16));
      }
#pragma unroll
      for (int i = 0; i < 4; ++i)
#pragma unroll
        for (int j = 0; j < 4; ++j)
          acc[i][j] = __builtin_amdgcn_mfma_f32_16x16x32_bf16(af[i], bg[j], acc[i][j], 0, 0, 0);
    }
#pragma unroll
    for (int i = 0; i < 4; ++i)
#pragma unroll
      for (int j = 0; j < 4; ++j) {
        int mbase = m0 + wr * 64 + i * 16 + ((lane >> 4) * 4);
        int n = n0 + wc * 64 + j * 16 + (lane & 15);
        float bb = bo[n];
#pragma unroll
        for (int r = 0; r < 4; ++r)
          out[(size_t)(mbase + r) * 512 + n] = acc[i][j][r] + bb;
      }
  }
}

extern "C" void kernel_launch(void* const* d_in, const int* in_sizes, int n_in,
                              void* d_out, int out_size, void* d_ws, size_t ws_size,
                              hipStream_t stream) {
  (void)in_sizes; (void)n_in; (void)out_size; (void)ws_size;
  const float* x = (const float*)d_in[0];
  const float* Wq = (const float*)d_in[1];
  const float* bq = (const float*)d_in[2];
  const float* Wk = (const float*)d_in[3];
  // d_in[4] (bk) unused: s0 is softmax-shift-invariant
  const float* Wv = (const float*)d_in[5];
  const float* bv = (const float*)d_in[6];
  const float* Wo = (const float*)d_in[7];
  const float* bo = (const float*)d_in[8];
  float* out = (float*)d_out;

  char* ws = (char*)d_ws;
  unsigned short* xb = (unsigned short*)(ws + 0);            // 67,108,864
  float* partial = (float*)(ws + 67108864);                  //  4,194,304
  float* s = (float*)(ws + 71303168);                        //  2,097,152
  float* P = (float*)(ws + 73400320);                        //    262,144
  unsigned short* XHV = (unsigned short*)(ws + 73662464);    // 16,777,216
  float* Ah = (float*)(ws + 90439680);                       //  2,097,152
  float* Av = (float*)(ws + 92536832);                       //  2,097,152
  unsigned short* WvT = (unsigned short*)(ws + 94633984);    //    524,288
  unsigned short* WoT = (unsigned short*)(ws + 95158272);    //     65,536
  // total ws use ~95.2 MB

  k_pool_prep<<<3200, 256, 0, stream>>>(x, xb, partial, Wv, Wo, WvT, WoT);
  k_qp2<<<dim3(16, 8), 256, 0, stream>>>(partial, Wq, bq, Wk, P);
  k_scores<<<1024, 256, 0, stream>>>(xb, P, s);
  k_xhv<<<dim3(2048, 2), 256, 0, stream>>>(xb, s, XHV);
  k_gemm2<<<dim3(32, 8), 256, 0, stream>>>(XHV, WvT, bv, Ah, Av);
  k_outgemm<<<dim3(2, 512), 256, 0, stream>>>(Ah, Av, WoT, bo, out);
}